// Round 14
// baseline (279.394 us; speedup 1.0000x reference)
//
#include <hip/hip_runtime.h>
#include <math.h>

#define BN_EPS 1e-5f

typedef _Float16 half8 __attribute__((ext_vector_type(8)));
typedef float f32x4 __attribute__((ext_vector_type(4)));

// ---------------------------------------------------------------------------
// prep: fold BN into weights/bias. (round-7 exact)
// ws layout: w1e[64*9]f32 @0 | b1e[64]f32 @2304B | b2e[32]f32 @2560 |
//            b3e[32]f32 @2688 | wT2e[9][32][64]h @2816 | wT3e[9][32][32]h @39680
// ---------------------------------------------------------------------------
__global__ __launch_bounds__(256) void prep_kernel(
    const float* __restrict__ w1, const float* __restrict__ b1,
    const float* __restrict__ g1, const float* __restrict__ be1,
    const float* __restrict__ m1, const float* __restrict__ v1,
    const float* __restrict__ w2, const float* __restrict__ b2,
    const float* __restrict__ g2, const float* __restrict__ be2,
    const float* __restrict__ m2, const float* __restrict__ v2,
    const float* __restrict__ w3, const float* __restrict__ b3,
    const float* __restrict__ g3, const float* __restrict__ be3,
    const float* __restrict__ m3, const float* __restrict__ v3,
    char* __restrict__ ws)
{
    float* w1e = (float*)ws;
    float* b1e = (float*)(ws + 2304);
    float* b2e = (float*)(ws + 2560);
    float* b3e = (float*)(ws + 2688);
    _Float16* wT2e = (_Float16*)(ws + 2816);
    _Float16* wT3e = (_Float16*)(ws + 39680);

    for (int t = threadIdx.x; t < 576; t += 256) {
        int oc = t / 9;
        float inv = g1[oc] * rsqrtf(v1[oc] + BN_EPS);
        w1e[t] = w1[t] * inv;
    }
    for (int t = threadIdx.x; t < 64; t += 256) {
        float inv = g1[t] * rsqrtf(v1[t] + BN_EPS);
        b1e[t] = b1[t] * inv + be1[t] - m1[t] * inv;
    }
    for (int t = threadIdx.x; t < 32; t += 256) {
        float inv2 = g2[t] * rsqrtf(v2[t] + BN_EPS);
        b2e[t] = b2[t] * inv2 + be2[t] - m2[t] * inv2;
        float inv3 = g3[t] * rsqrtf(v3[t] + BN_EPS);
        b3e[t] = b3[t] * inv3 + be3[t] - m3[t] * inv3;
    }
    for (int t = threadIdx.x; t < 18432; t += 256) {
        int r = t / 2048; int rem = t - r * 2048;
        int oc = rem >> 6; int ic = rem & 63;
        float inv = g2[oc] * rsqrtf(v2[oc] + BN_EPS);
        wT2e[t] = (_Float16)(w2[(oc * 64 + ic) * 9 + r] * inv);
    }
    for (int t = threadIdx.x; t < 9216; t += 256) {
        int r = t / 1024; int rem = t - r * 1024;
        int oc = rem >> 5; int ic = rem & 31;
        float inv = g3[oc] * rsqrtf(v3[oc] + BN_EPS);
        wT3e[t] = (_Float16)(w3[(oc * 32 + ic) * 9 + r] * inv);
    }
}

// ---------------------------------------------------------------------------
// F12: fused conv1+conv2 — ROUND-7 EXACT (best measured 125us, no spill).
// ---------------------------------------------------------------------------
__global__ __launch_bounds__(256, 3) void f12_kernel(
    const float* __restrict__ x, const char* __restrict__ wsw,
    _Float16* __restrict__ h2)
{
    const float* w1e = (const float*)wsw;
    const float* b1e = (const float*)(wsw + 2304);
    const float* b2e = (const float*)(wsw + 2560);
    const _Float16* wT2e = (const _Float16*)(wsw + 2816);

    constexpr int PSTR = 36;            // halves per pixel slot (32 + 4 pad)
    __shared__ float sX[20 * 20];
    __shared__ _Float16 sH1[324 * PSTR];

    const int t = threadIdx.x, lane = t & 63, w = t >> 6;
    const int tl = lane & 15, g = lane >> 4;
    const int img = blockIdx.z;
    const int x0 = blockIdx.x * 16, y0 = blockIdx.y * 16;

    // ---- stage x patch (20x20, pad-0 OOB) ----
    const float* xb = x + (size_t)img * 16384;
    for (int idx = t; idx < 400; idx += 256) {
        int r = idx / 20, c = idx - r * 20;
        int iy = y0 - 4 + r, ix = x0 - 4 + c;
        sX[idx] = (iy >= 0 && iy < 128 && ix >= 0 && ix < 128)
                      ? xb[iy * 128 + ix] : 0.f;
    }
    __syncthreads();

    f32x4 acc[4][2];
#pragma unroll
    for (int pf = 0; pf < 4; pf++)
#pragma unroll
        for (int of = 0; of < 2; of++) acc[pf][of] = (f32x4){0.f, 0.f, 0.f, 0.f};

#pragma unroll
    for (int h = 0; h < 2; h++) {
        // ---- phase 1: conv1 for oc [32h, 32h+32) into sH1 ----
        {
            const int ocg = __builtin_amdgcn_readfirstlane(t >> 6);
            const int pxslot = t & 63;
            float wreg[8][9];
            float bb[8];
#pragma unroll
            for (int j = 0; j < 8; j++) {
                int oc = h * 32 + ocg * 8 + j;
                bb[j] = b1e[oc];
#pragma unroll
                for (int k = 0; k < 9; k++) wreg[j][k] = w1e[oc * 9 + k];
            }
#pragma unroll
            for (int round = 0; round < 6; round++) {
                int px = pxslot + round * 64;
                if (px < 324) {
                    int py = px / 18, pxx = px - py * 18;
                    float a[9];
#pragma unroll
                    for (int ky = 0; ky < 3; ky++)
#pragma unroll
                        for (int kx = 0; kx < 3; kx++)
                            a[ky * 3 + kx] = sX[(py + ky) * 20 + pxx + kx];
                    half8 hv;
#pragma unroll
                    for (int j = 0; j < 8; j++) {
                        float acc1 = bb[j];
#pragma unroll
                        for (int k = 0; k < 9; k++)
                            acc1 = fmaf(a[k], wreg[j][k], acc1);
                        hv[j] = (_Float16)fmaxf(acc1, 0.f);
                    }
                    *(half8*)(&sH1[px * PSTR + ocg * 8]) = hv;
                }
            }
        }
        __syncthreads();                 // sH1 ready for MFMA

        // ---- phase 2: conv2 MFMA over this 32-ic chunk; wf loaded per tap ----
#pragma unroll
        for (int r = 0; r < 9; r++) {
            const int ky = r / 3, kx = r - ky * 3;
            half8 wf0 = *(const half8*)(
                wT2e + (r * 32 + tl) * 64 + h * 32 + g * 8);
            half8 wf1 = *(const half8*)(
                wT2e + (r * 32 + 16 + tl) * 64 + h * 32 + g * 8);
#pragma unroll
            for (int pf = 0; pf < 4; pf++) {
                const int yl = w * 4 + pf + ky;
                half8 af = *(const half8*)(
                    &sH1[(yl * 18 + tl + kx) * PSTR + g * 8]);
                acc[pf][0] = __builtin_amdgcn_mfma_f32_16x16x32_f16(
                    af, wf0, acc[pf][0], 0, 0, 0);
                acc[pf][1] = __builtin_amdgcn_mfma_f32_16x16x32_f16(
                    af, wf1, acc[pf][1], 0, 0, 0);
            }
        }
        if (h == 0) __syncthreads();     // sH1 readers done before overwrite
    }

    // ---- epilogue ----
    const float bb0 = b2e[tl], bb1 = b2e[16 + tl];
    _Float16* outb = h2 + (size_t)img * 132 * 132 * 32;
#pragma unroll
    for (int pf = 0; pf < 4; pf++) {
        int y = y0 + w * 4 + pf;
        if (y >= 132) continue;
#pragma unroll
        for (int i = 0; i < 4; i++) {
            int xc = x0 + 4 * g + i;
            if (xc >= 132) continue;
            _Float16* q = outb + ((size_t)y * 132 + xc) * 32 + tl;
            q[0]  = (_Float16)fmaxf(acc[pf][0][i] + bb0, 0.f);
            q[16] = (_Float16)fmaxf(acc[pf][1][i] + bb1, 0.f);
        }
    }
}

// ---------------------------------------------------------------------------
// conv3: h2 -> h3, MFMA, folded BN3. (round-7 exact)
// ---------------------------------------------------------------------------
__global__ __launch_bounds__(256, 3) void conv3_kernel(
    const _Float16* __restrict__ in, const char* __restrict__ wsw,
    _Float16* __restrict__ out)
{
    const float* b3e = (const float*)(wsw + 2688);
    const _Float16* wT3e = (const _Float16*)(wsw + 39680);

    constexpr int HIN = 132, WIN = 132, HOUT = 130, WOUT = 130;
    constexpr int PSTR = 40;
    __shared__ _Float16 sIn[324 * PSTR];

    const int t = threadIdx.x, lane = t & 63, w = t >> 6;
    const int tl = lane & 15, g = lane >> 4;
    const int img = 63 - blockIdx.z;          // reverse order (L3 LIFO)
    const int x0 = blockIdx.x * 16, y0 = blockIdx.y * 16;

    const _Float16* inb = in + (size_t)img * HIN * WIN * 32;

    for (int kk = 0; kk < 6; kk++) {
        int idx = t + kk * 256;
        if (idx < 1296) {
            int px = idx >> 2, sg = idx & 3;
            int py = px / 18, pxx = px - py * 18;
            int iy = y0 + py, ix = x0 + pxx;
            half8 v = (half8){0, 0, 0, 0, 0, 0, 0, 0};
            if (iy < HIN && ix < WIN)
                v = *(const half8*)(inb + ((size_t)iy * WIN + ix) * 32 + sg * 8);
            *(half8*)(&sIn[px * PSTR + sg * 8]) = v;
        }
    }

    f32x4 acc[4][2];
#pragma unroll
    for (int pf = 0; pf < 4; pf++)
#pragma unroll
        for (int of = 0; of < 2; of++) acc[pf][of] = (f32x4){0.f, 0.f, 0.f, 0.f};

    __syncthreads();

#pragma unroll
    for (int r = 0; r < 9; r++) {
        const int ky = r / 3, kx = r - ky * 3;
        half8 wf0 = *(const half8*)(wT3e + (r * 32 + tl) * 32 + g * 8);
        half8 wf1 = *(const half8*)(wT3e + (r * 32 + 16 + tl) * 32 + g * 8);
#pragma unroll
        for (int pf = 0; pf < 4; pf++) {
            const int yl = w * 4 + pf + ky;
            half8 af = *(const half8*)(&sIn[(yl * 18 + tl + kx) * PSTR + g * 8]);
            acc[pf][0] = __builtin_amdgcn_mfma_f32_16x16x32_f16(
                af, wf0, acc[pf][0], 0, 0, 0);
            acc[pf][1] = __builtin_amdgcn_mfma_f32_16x16x32_f16(
                af, wf1, acc[pf][1], 0, 0, 0);
        }
    }

    const float bb0 = b3e[tl], bb1 = b3e[16 + tl];
    _Float16* outb = out + (size_t)img * HOUT * WOUT * 32;
#pragma unroll
    for (int pf = 0; pf < 4; pf++) {
        int y = y0 + w * 4 + pf;
        if (y >= HOUT) continue;
#pragma unroll
        for (int i = 0; i < 4; i++) {
            int xc = x0 + 4 * g + i;
            if (xc >= WOUT) continue;
            _Float16* q = outb + ((size_t)y * WOUT + xc) * 32 + tl;
            q[0]  = (_Float16)fmaxf(acc[pf][0][i] + bb0, 0.f);
            q[16] = (_Float16)fmaxf(acc[pf][1][i] + bb1, 0.f);
        }
    }
}

// ---------------------------------------------------------------------------
// conv4 v3 + grid stats: h3 18x18x32 patch STAGED IN LDS (coalesced bulk,
// conv3's validated pattern; always in-bounds at x0,y0<=112 on a 130-wide
// field), then conv4 math from LDS (f34-v2 validated body) + stats.
// Replaces 9216 scattered per-lane global loads/block with 1296 coalesced.
// ---------------------------------------------------------------------------
__global__ __launch_bounds__(256, 2) void conv4_kernel(
    const _Float16* __restrict__ h3, const float* __restrict__ w4,
    const float* __restrict__ b4, float* __restrict__ heat,
    float* __restrict__ stats)
{
    constexpr int PSTR = 36;
    __shared__ _Float16 sH3[324 * PSTR];
    __shared__ float sw[288];
    __shared__ float sS[256];

    const int img = blockIdx.z;
    const int x0 = blockIdx.x * 16, y0 = blockIdx.y * 16;
    const int t = threadIdx.x;

    for (int i = t; i < 288; i += 256) sw[i] = w4[i];

    // ---- stage 18x18x32 h3 patch (always in-bounds) ----
    const _Float16* hb = h3 + (size_t)img * 130 * 130 * 32;
#pragma unroll
    for (int kk = 0; kk < 6; kk++) {
        int idx = t + kk * 256;
        if (idx < 1296) {
            int px = idx >> 2, sg = idx & 3;
            int py = px / 18, pxx = px - py * 18;
            half8 v = *(const half8*)(
                hb + ((size_t)(y0 + py) * 130 + (x0 + pxx)) * 32 + sg * 8);
            *(half8*)(&sH3[px * PSTR + sg * 8]) = v;
        }
    }
    __syncthreads();

    // ---- conv4 from sH3 (validated math), heat out ----
    const int ty = t >> 4, tx = t & 15;
    float acc = b4[0];
#pragma unroll
    for (int r = 0; r < 9; r++) {
        const int ky = r / 3, kx = r - ky * 3;
        const _Float16* p = &sH3[((ty + ky) * 18 + tx + kx) * PSTR];
        half8 v0 = *(const half8*)(p);
        half8 v1 = *(const half8*)(p + 8);
        half8 v2 = *(const half8*)(p + 16);
        half8 v3 = *(const half8*)(p + 24);
#pragma unroll
        for (int j = 0; j < 8; j++) {
            acc = fmaf((float)v0[j], sw[(j) * 9 + r], acc);
            acc = fmaf((float)v1[j], sw[(8 + j) * 9 + r], acc);
            acc = fmaf((float)v2[j], sw[(16 + j) * 9 + r], acc);
            acc = fmaf((float)v3[j], sw[(24 + j) * 9 + r], acc);
        }
    }
    heat[(size_t)img * 16384 + (y0 + ty) * 128 + (x0 + tx)] = acc;
    sS[t] = 1.0f / (1.0f + expf(-acc));
    __syncthreads();

    // ---- per-cell stats (validated reduction verbatim) ----
    const int w = t >> 6, l = t & 63;
    const int cy = w >> 1, cx = w & 1;
    const int ly = cy * 8 + (l >> 3), lx = cx * 8 + (l & 7);
    float v = sS[ly * 16 + lx];
    float mx = v, s = v;
    float sx = v * ((float)(x0 + lx) * (1.0f / 127.0f));
    float sy = v * ((float)(y0 + ly) * (1.0f / 127.0f));
#pragma unroll
    for (int off = 1; off < 64; off <<= 1) {
        mx = fmaxf(mx, __shfl_xor(mx, off));
        s += __shfl_xor(s, off);
        sx += __shfl_xor(sx, off);
        sy += __shfl_xor(sy, off);
    }
    if (l == 0) {
        int cell = (blockIdx.y * 2 + cy) * 16 + blockIdx.x * 2 + cx;
        float4* st = (float4*)(stats + ((size_t)img * 256 + cell) * 4);
        *st = make_float4(mx, s, sx, sy);
    }
}

// ---------------------------------------------------------------------------
// nodes2 (round-7 exact)
// ---------------------------------------------------------------------------
__global__ __launch_bounds__(256) void nodes2_kernel(
    const float* __restrict__ stats, float* __restrict__ nodes,
    float* __restrict__ valid, float* __restrict__ counts)
{
    int b = blockIdx.x;
    int gsl = threadIdx.x;
    float4 st = ((const float4*)stats)[b * 256 + gsl];
    float mx = st.x, s = st.y, sx = st.z, sy = st.w;

    __shared__ float gv[256];
    gv[gsl] = mx;
    __syncthreads();

    int cgt = 0, ceq = 0;
    for (int j = 0; j < 256; j++) {
        float vj = gv[j];
        cgt += (vj > mx) ? 1 : 0;
        ceq += (vj == mx) ? 1 : 0;
    }
    __shared__ float kth;
    if (cgt <= 16 && 16 < cgt + ceq) kth = mx;
    __syncthreads();

    float thresh = fmaxf(kth, 0.9f);
    bool val = mx > thresh;
    nodes[((size_t)b * 256 + gsl) * 2 + 0] = val ? sx / s : 0.f;
    nodes[((size_t)b * 256 + gsl) * 2 + 1] = val ? sy / s : 0.f;
    valid[(size_t)b * 256 + gsl] = val ? 1.f : 0.f;

    unsigned long long ball = __ballot(val);
    __shared__ int wc[4];
    if ((gsl & 63) == 0) wc[gsl >> 6] = __popcll(ball);
    __syncthreads();
    if (gsl == 0) counts[b] = (float)(wc[0] + wc[1] + wc[2] + wc[3]);
}

// ---------------------------------------------------------------------------
extern "C" void kernel_launch(void* const* d_in, const int* in_sizes, int n_in,
                              void* d_out, int out_size, void* d_ws, size_t ws_size,
                              hipStream_t stream)
{
    const float* x   = (const float*)d_in[0];
    const float* w1  = (const float*)d_in[1];
    const float* b1  = (const float*)d_in[2];
    const float* g1  = (const float*)d_in[3];
    const float* be1 = (const float*)d_in[4];
    const float* m1  = (const float*)d_in[5];
    const float* v1  = (const float*)d_in[6];
    const float* w2  = (const float*)d_in[7];
    const float* b2  = (const float*)d_in[8];
    const float* g2  = (const float*)d_in[9];
    const float* be2 = (const float*)d_in[10];
    const float* m2  = (const float*)d_in[11];
    const float* v2  = (const float*)d_in[12];
    const float* w3  = (const float*)d_in[13];
    const float* b3  = (const float*)d_in[14];
    const float* g3  = (const float*)d_in[15];
    const float* be3 = (const float*)d_in[16];
    const float* m3  = (const float*)d_in[17];
    const float* v3  = (const float*)d_in[18];
    const float* w4  = (const float*)d_in[19];
    const float* b4  = (const float*)d_in[20];

    float* out = (float*)d_out;
    float* out_nodes = out;                           // [64][256][2]
    float* out_heat  = out + 32768;                   // [64][128][128]
    float* out_valid = out + 32768 + 1048576;         // [64][256]
    float* out_count = out + 32768 + 1048576 + 16384; // [64]

    char* ws = (char*)d_ws;
    const size_t WREGION = 65536;
    float* stats = (float*)(ws + WREGION);                      // 64*256*4 f32
    _Float16* h2 = (_Float16*)(ws + WREGION + 262144);          // 64*17424*32 h
    _Float16* h3 = h2 + (size_t)64 * 17424 * 32;                // 64*16900*32 h

    prep_kernel<<<1, 256, 0, stream>>>(w1, b1, g1, be1, m1, v1,
                                       w2, b2, g2, be2, m2, v2,
                                       w3, b3, g3, be3, m3, v3, ws);

    dim3 gd(9, 9, 64);
    f12_kernel<<<gd, 256, 0, stream>>>(x, ws, h2);
    conv3_kernel<<<gd, 256, 0, stream>>>(h2, ws, h3);

    dim3 gd4(8, 8, 64);
    conv4_kernel<<<gd4, 256, 0, stream>>>(h3, w4, b4, out_heat, stats);

    nodes2_kernel<<<64, 256, 0, stream>>>(stats, out_nodes, out_valid, out_count);
}

// Round 15
// 223.145 us; speedup vs baseline: 1.2521x; 1.2521x over previous
//
#include <hip/hip_runtime.h>
#include <math.h>

#define BN_EPS 1e-5f

typedef _Float16 half8 __attribute__((ext_vector_type(8)));
typedef float f32x4 __attribute__((ext_vector_type(4)));

// ---------------------------------------------------------------------------
// prep: fold BN into weights/bias. (round-7 math, gridded across 16 blocks)
// ws layout: w1e[64*9]f32 @0 | b1e[64]f32 @2304B | b2e[32]f32 @2560 |
//            b3e[32]f32 @2688 | wT2e[9][32][64]h @2816 | wT3e[9][32][32]h @39680
// ---------------------------------------------------------------------------
__global__ __launch_bounds__(256) void prep_kernel(
    const float* __restrict__ w1, const float* __restrict__ b1,
    const float* __restrict__ g1, const float* __restrict__ be1,
    const float* __restrict__ m1, const float* __restrict__ v1,
    const float* __restrict__ w2, const float* __restrict__ b2,
    const float* __restrict__ g2, const float* __restrict__ be2,
    const float* __restrict__ m2, const float* __restrict__ v2,
    const float* __restrict__ w3, const float* __restrict__ b3,
    const float* __restrict__ g3, const float* __restrict__ be3,
    const float* __restrict__ m3, const float* __restrict__ v3,
    char* __restrict__ ws)
{
    float* w1e = (float*)ws;
    float* b1e = (float*)(ws + 2304);
    float* b2e = (float*)(ws + 2560);
    float* b3e = (float*)(ws + 2688);
    _Float16* wT2e = (_Float16*)(ws + 2816);
    _Float16* wT3e = (_Float16*)(ws + 39680);

    const int t0 = blockIdx.x * 256 + threadIdx.x;
    const int stride = gridDim.x * 256;

    for (int t = t0; t < 576; t += stride) {
        int oc = t / 9;
        float inv = g1[oc] * rsqrtf(v1[oc] + BN_EPS);
        w1e[t] = w1[t] * inv;
    }
    for (int t = t0; t < 64; t += stride) {
        float inv = g1[t] * rsqrtf(v1[t] + BN_EPS);
        b1e[t] = b1[t] * inv + be1[t] - m1[t] * inv;
    }
    for (int t = t0; t < 32; t += stride) {
        float inv2 = g2[t] * rsqrtf(v2[t] + BN_EPS);
        b2e[t] = b2[t] * inv2 + be2[t] - m2[t] * inv2;
        float inv3 = g3[t] * rsqrtf(v3[t] + BN_EPS);
        b3e[t] = b3[t] * inv3 + be3[t] - m3[t] * inv3;
    }
    for (int t = t0; t < 18432; t += stride) {
        int r = t / 2048; int rem = t - r * 2048;
        int oc = rem >> 6; int ic = rem & 63;
        float inv = g2[oc] * rsqrtf(v2[oc] + BN_EPS);
        wT2e[t] = (_Float16)(w2[(oc * 64 + ic) * 9 + r] * inv);
    }
    for (int t = t0; t < 9216; t += stride) {
        int r = t / 1024; int rem = t - r * 1024;
        int oc = rem >> 5; int ic = rem & 31;
        float inv = g3[oc] * rsqrtf(v3[oc] + BN_EPS);
        wT3e[t] = (_Float16)(w3[(oc * 32 + ic) * 9 + r] * inv);
    }
}

// ---------------------------------------------------------------------------
// F12: fused conv1+conv2 — ROUND-7 EXACT (best measured 125us, no spill).
// ---------------------------------------------------------------------------
__global__ __launch_bounds__(256, 3) void f12_kernel(
    const float* __restrict__ x, const char* __restrict__ wsw,
    _Float16* __restrict__ h2)
{
    const float* w1e = (const float*)wsw;
    const float* b1e = (const float*)(wsw + 2304);
    const float* b2e = (const float*)(wsw + 2560);
    const _Float16* wT2e = (const _Float16*)(wsw + 2816);

    constexpr int PSTR = 36;            // halves per pixel slot (32 + 4 pad)
    __shared__ float sX[20 * 20];
    __shared__ _Float16 sH1[324 * PSTR];

    const int t = threadIdx.x, lane = t & 63, w = t >> 6;
    const int tl = lane & 15, g = lane >> 4;
    const int img = blockIdx.z;
    const int x0 = blockIdx.x * 16, y0 = blockIdx.y * 16;

    // ---- stage x patch (20x20, pad-0 OOB) ----
    const float* xb = x + (size_t)img * 16384;
    for (int idx = t; idx < 400; idx += 256) {
        int r = idx / 20, c = idx - r * 20;
        int iy = y0 - 4 + r, ix = x0 - 4 + c;
        sX[idx] = (iy >= 0 && iy < 128 && ix >= 0 && ix < 128)
                      ? xb[iy * 128 + ix] : 0.f;
    }
    __syncthreads();

    f32x4 acc[4][2];
#pragma unroll
    for (int pf = 0; pf < 4; pf++)
#pragma unroll
        for (int of = 0; of < 2; of++) acc[pf][of] = (f32x4){0.f, 0.f, 0.f, 0.f};

#pragma unroll
    for (int h = 0; h < 2; h++) {
        // ---- phase 1: conv1 for oc [32h, 32h+32) into sH1 ----
        {
            const int ocg = __builtin_amdgcn_readfirstlane(t >> 6);
            const int pxslot = t & 63;
            float wreg[8][9];
            float bb[8];
#pragma unroll
            for (int j = 0; j < 8; j++) {
                int oc = h * 32 + ocg * 8 + j;
                bb[j] = b1e[oc];
#pragma unroll
                for (int k = 0; k < 9; k++) wreg[j][k] = w1e[oc * 9 + k];
            }
#pragma unroll
            for (int round = 0; round < 6; round++) {
                int px = pxslot + round * 64;
                if (px < 324) {
                    int py = px / 18, pxx = px - py * 18;
                    float a[9];
#pragma unroll
                    for (int ky = 0; ky < 3; ky++)
#pragma unroll
                        for (int kx = 0; kx < 3; kx++)
                            a[ky * 3 + kx] = sX[(py + ky) * 20 + pxx + kx];
                    half8 hv;
#pragma unroll
                    for (int j = 0; j < 8; j++) {
                        float acc1 = bb[j];
#pragma unroll
                        for (int k = 0; k < 9; k++)
                            acc1 = fmaf(a[k], wreg[j][k], acc1);
                        hv[j] = (_Float16)fmaxf(acc1, 0.f);
                    }
                    *(half8*)(&sH1[px * PSTR + ocg * 8]) = hv;
                }
            }
        }
        __syncthreads();                 // sH1 ready for MFMA

        // ---- phase 2: conv2 MFMA over this 32-ic chunk; wf loaded per tap ----
#pragma unroll
        for (int r = 0; r < 9; r++) {
            const int ky = r / 3, kx = r - ky * 3;
            half8 wf0 = *(const half8*)(
                wT2e + (r * 32 + tl) * 64 + h * 32 + g * 8);
            half8 wf1 = *(const half8*)(
                wT2e + (r * 32 + 16 + tl) * 64 + h * 32 + g * 8);
#pragma unroll
            for (int pf = 0; pf < 4; pf++) {
                const int yl = w * 4 + pf + ky;
                half8 af = *(const half8*)(
                    &sH1[(yl * 18 + tl + kx) * PSTR + g * 8]);
                acc[pf][0] = __builtin_amdgcn_mfma_f32_16x16x32_f16(
                    af, wf0, acc[pf][0], 0, 0, 0);
                acc[pf][1] = __builtin_amdgcn_mfma_f32_16x16x32_f16(
                    af, wf1, acc[pf][1], 0, 0, 0);
            }
        }
        if (h == 0) __syncthreads();     // sH1 readers done before overwrite
    }

    // ---- epilogue ----
    const float bb0 = b2e[tl], bb1 = b2e[16 + tl];
    _Float16* outb = h2 + (size_t)img * 132 * 132 * 32;
#pragma unroll
    for (int pf = 0; pf < 4; pf++) {
        int y = y0 + w * 4 + pf;
        if (y >= 132) continue;
#pragma unroll
        for (int i = 0; i < 4; i++) {
            int xc = x0 + 4 * g + i;
            if (xc >= 132) continue;
            _Float16* q = outb + ((size_t)y * 132 + xc) * 32 + tl;
            q[0]  = (_Float16)fmaxf(acc[pf][0][i] + bb0, 0.f);
            q[16] = (_Float16)fmaxf(acc[pf][1][i] + bb1, 0.f);
        }
    }
}

// ---------------------------------------------------------------------------
// conv3: h2 -> h3, MFMA, folded BN3. (round-7 exact)
// ---------------------------------------------------------------------------
__global__ __launch_bounds__(256, 3) void conv3_kernel(
    const _Float16* __restrict__ in, const char* __restrict__ wsw,
    _Float16* __restrict__ out)
{
    const float* b3e = (const float*)(wsw + 2688);
    const _Float16* wT3e = (const _Float16*)(wsw + 39680);

    constexpr int HIN = 132, WIN = 132, HOUT = 130, WOUT = 130;
    constexpr int PSTR = 40;
    __shared__ _Float16 sIn[324 * PSTR];

    const int t = threadIdx.x, lane = t & 63, w = t >> 6;
    const int tl = lane & 15, g = lane >> 4;
    const int img = 63 - blockIdx.z;          // reverse order (L3 LIFO)
    const int x0 = blockIdx.x * 16, y0 = blockIdx.y * 16;

    const _Float16* inb = in + (size_t)img * HIN * WIN * 32;

    for (int kk = 0; kk < 6; kk++) {
        int idx = t + kk * 256;
        if (idx < 1296) {
            int px = idx >> 2, sg = idx & 3;
            int py = px / 18, pxx = px - py * 18;
            int iy = y0 + py, ix = x0 + pxx;
            half8 v = (half8){0, 0, 0, 0, 0, 0, 0, 0};
            if (iy < HIN && ix < WIN)
                v = *(const half8*)(inb + ((size_t)iy * WIN + ix) * 32 + sg * 8);
            *(half8*)(&sIn[px * PSTR + sg * 8]) = v;
        }
    }

    f32x4 acc[4][2];
#pragma unroll
    for (int pf = 0; pf < 4; pf++)
#pragma unroll
        for (int of = 0; of < 2; of++) acc[pf][of] = (f32x4){0.f, 0.f, 0.f, 0.f};

    __syncthreads();

#pragma unroll
    for (int r = 0; r < 9; r++) {
        const int ky = r / 3, kx = r - ky * 3;
        half8 wf0 = *(const half8*)(wT3e + (r * 32 + tl) * 32 + g * 8);
        half8 wf1 = *(const half8*)(wT3e + (r * 32 + 16 + tl) * 32 + g * 8);
#pragma unroll
        for (int pf = 0; pf < 4; pf++) {
            const int yl = w * 4 + pf + ky;
            half8 af = *(const half8*)(&sIn[(yl * 18 + tl + kx) * PSTR + g * 8]);
            acc[pf][0] = __builtin_amdgcn_mfma_f32_16x16x32_f16(
                af, wf0, acc[pf][0], 0, 0, 0);
            acc[pf][1] = __builtin_amdgcn_mfma_f32_16x16x32_f16(
                af, wf1, acc[pf][1], 0, 0, 0);
        }
    }

    const float bb0 = b3e[tl], bb1 = b3e[16 + tl];
    _Float16* outb = out + (size_t)img * HOUT * WOUT * 32;
#pragma unroll
    for (int pf = 0; pf < 4; pf++) {
        int y = y0 + w * 4 + pf;
        if (y >= HOUT) continue;
#pragma unroll
        for (int i = 0; i < 4; i++) {
            int xc = x0 + 4 * g + i;
            if (xc >= WOUT) continue;
            _Float16* q = outb + ((size_t)y * WOUT + xc) * 32 + tl;
            q[0]  = (_Float16)fmaxf(acc[pf][0][i] + bb0, 0.f);
            q[16] = (_Float16)fmaxf(acc[pf][1][i] + bb1, 0.f);
        }
    }
}

// ---------------------------------------------------------------------------
// conv4 + grid stats (round-7 exact: thread-per-pixel, scattered loads that
// L1-hit; fused sigmoid + per-cell stats reduction)
// ---------------------------------------------------------------------------
__global__ __launch_bounds__(256) void conv4_kernel(
    const _Float16* __restrict__ h3, const float* __restrict__ w4,
    const float* __restrict__ b4, float* __restrict__ heat,
    float* __restrict__ stats)
{
    const int img = blockIdx.z;
    const int x0 = blockIdx.x * 16, y0 = blockIdx.y * 16;
    const int t = threadIdx.x;
    const int ty = t >> 4, tx = t & 15;

    __shared__ float sw[288];
    __shared__ float sS[256];
    for (int i = t; i < 288; i += 256) sw[i] = w4[i];
    __syncthreads();

    const int y = y0 + ty, x = x0 + tx;
    const _Float16* hb = h3 + (size_t)img * 130 * 130 * 32;
    float acc = b4[0];
#pragma unroll
    for (int r = 0; r < 9; r++) {
        const int ky = r / 3, kx = r - ky * 3;
        const _Float16* p = hb + ((size_t)(y + ky) * 130 + (x + kx)) * 32;
        half8 v0 = *(const half8*)(p);
        half8 v1 = *(const half8*)(p + 8);
        half8 v2 = *(const half8*)(p + 16);
        half8 v3 = *(const half8*)(p + 24);
#pragma unroll
        for (int j = 0; j < 8; j++) {
            acc = fmaf((float)v0[j], sw[(j) * 9 + r], acc);
            acc = fmaf((float)v1[j], sw[(8 + j) * 9 + r], acc);
            acc = fmaf((float)v2[j], sw[(16 + j) * 9 + r], acc);
            acc = fmaf((float)v3[j], sw[(24 + j) * 9 + r], acc);
        }
    }
    heat[(size_t)img * 16384 + y * 128 + x] = acc;
    sS[t] = 1.0f / (1.0f + expf(-acc));
    __syncthreads();

    const int w = t >> 6, l = t & 63;
    const int cy = w >> 1, cx = w & 1;
    const int ly = cy * 8 + (l >> 3), lx = cx * 8 + (l & 7);
    float v = sS[ly * 16 + lx];
    float mx = v, s = v;
    float sx = v * ((float)(x0 + lx) * (1.0f / 127.0f));
    float sy = v * ((float)(y0 + ly) * (1.0f / 127.0f));
#pragma unroll
    for (int off = 1; off < 64; off <<= 1) {
        mx = fmaxf(mx, __shfl_xor(mx, off));
        s += __shfl_xor(s, off);
        sx += __shfl_xor(sx, off);
        sy += __shfl_xor(sy, off);
    }
    if (l == 0) {
        int cell = (blockIdx.y * 2 + cy) * 16 + blockIdx.x * 2 + cx;
        float4* st = (float4*)(stats + ((size_t)img * 256 + cell) * 4);
        *st = make_float4(mx, s, sx, sy);
    }
}

// ---------------------------------------------------------------------------
// nodes2 (round-7 exact)
// ---------------------------------------------------------------------------
__global__ __launch_bounds__(256) void nodes2_kernel(
    const float* __restrict__ stats, float* __restrict__ nodes,
    float* __restrict__ valid, float* __restrict__ counts)
{
    int b = blockIdx.x;
    int gsl = threadIdx.x;
    float4 st = ((const float4*)stats)[b * 256 + gsl];
    float mx = st.x, s = st.y, sx = st.z, sy = st.w;

    __shared__ float gv[256];
    gv[gsl] = mx;
    __syncthreads();

    int cgt = 0, ceq = 0;
    for (int j = 0; j < 256; j++) {
        float vj = gv[j];
        cgt += (vj > mx) ? 1 : 0;
        ceq += (vj == mx) ? 1 : 0;
    }
    __shared__ float kth;
    if (cgt <= 16 && 16 < cgt + ceq) kth = mx;
    __syncthreads();

    float thresh = fmaxf(kth, 0.9f);
    bool val = mx > thresh;
    nodes[((size_t)b * 256 + gsl) * 2 + 0] = val ? sx / s : 0.f;
    nodes[((size_t)b * 256 + gsl) * 2 + 1] = val ? sy / s : 0.f;
    valid[(size_t)b * 256 + gsl] = val ? 1.f : 0.f;

    unsigned long long ball = __ballot(val);
    __shared__ int wc[4];
    if ((gsl & 63) == 0) wc[gsl >> 6] = __popcll(ball);
    __syncthreads();
    if (gsl == 0) counts[b] = (float)(wc[0] + wc[1] + wc[2] + wc[3]);
}

// ---------------------------------------------------------------------------
extern "C" void kernel_launch(void* const* d_in, const int* in_sizes, int n_in,
                              void* d_out, int out_size, void* d_ws, size_t ws_size,
                              hipStream_t stream)
{
    const float* x   = (const float*)d_in[0];
    const float* w1  = (const float*)d_in[1];
    const float* b1  = (const float*)d_in[2];
    const float* g1  = (const float*)d_in[3];
    const float* be1 = (const float*)d_in[4];
    const float* m1  = (const float*)d_in[5];
    const float* v1  = (const float*)d_in[6];
    const float* w2  = (const float*)d_in[7];
    const float* b2  = (const float*)d_in[8];
    const float* g2  = (const float*)d_in[9];
    const float* be2 = (const float*)d_in[10];
    const float* m2  = (const float*)d_in[11];
    const float* v2  = (const float*)d_in[12];
    const float* w3  = (const float*)d_in[13];
    const float* b3  = (const float*)d_in[14];
    const float* g3  = (const float*)d_in[15];
    const float* be3 = (const float*)d_in[16];
    const float* m3  = (const float*)d_in[17];
    const float* v3  = (const float*)d_in[18];
    const float* w4  = (const float*)d_in[19];
    const float* b4  = (const float*)d_in[20];

    float* out = (float*)d_out;
    float* out_nodes = out;                           // [64][256][2]
    float* out_heat  = out + 32768;                   // [64][128][128]
    float* out_valid = out + 32768 + 1048576;         // [64][256]
    float* out_count = out + 32768 + 1048576 + 16384; // [64]

    char* ws = (char*)d_ws;
    const size_t WREGION = 65536;
    float* stats = (float*)(ws + WREGION);                      // 64*256*4 f32
    _Float16* h2 = (_Float16*)(ws + WREGION + 262144);          // 64*17424*32 h
    _Float16* h3 = h2 + (size_t)64 * 17424 * 32;                // 64*16900*32 h

    prep_kernel<<<16, 256, 0, stream>>>(w1, b1, g1, be1, m1, v1,
                                        w2, b2, g2, be2, m2, v2,
                                        w3, b3, g3, be3, m3, v3, ws);

    dim3 gd(9, 9, 64);
    f12_kernel<<<gd, 256, 0, stream>>>(x, ws, h2);
    conv3_kernel<<<gd, 256, 0, stream>>>(h2, ws, h3);

    dim3 gd4(8, 8, 64);
    conv4_kernel<<<gd4, 256, 0, stream>>>(h3, w4, b4, out_heat, stats);

    nodes2_kernel<<<64, 256, 0, stream>>>(stats, out_nodes, out_valid, out_count);
}